// Round 13
// baseline (52.866 us; speedup 1.0000x reference)
//
#include <hip/hip_runtime.h>

#define NEGV -1.0e12f
constexpr int B = 16, C = 384, Q = 64, D = 2048;
constexpr int PITCH = 40;      // shorts per packed row (80 B, 2-way banks)
constexpr int IST = 8320;      // shorts per 32-k image (208 rows x 40 = 16640 B)
constexpr int NIMG = 64;       // 32-k images per batch
constexpr int NT = 96;         // c-rows per k_score block (n-tile)
constexpr int KC = 8;          // split-K chunks (256 k each, 8 images)
constexpr int SP = 208;        // S3 partial col pitch

typedef __attribute__((ext_vector_type(8))) short s16x8;
typedef __attribute__((ext_vector_type(4))) float f32x4;

__device__ __forceinline__ unsigned pkbf(float lo, float hi) {
  unsigned ulo = __builtin_bit_cast(unsigned, lo);
  unsigned uhi = __builtin_bit_cast(unsigned, hi);
  return (uhi & 0xFFFF0000u) | (ulo >> 16);
}
__device__ __forceinline__ float bflo(unsigned u) {
  return __builtin_bit_cast(float, u << 16);
}
__device__ __forceinline__ float bfhi(unsigned u) {
  return __builtin_bit_cast(float, u & 0xFFFF0000u);
}

#define GLD_LDS(gsrc, ldst)                                              \
  __builtin_amdgcn_global_load_lds(                                      \
      (const __attribute__((address_space(1))) unsigned*)(gsrc),         \
      (__attribute__((address_space(3))) unsigned*)(ldst), 16, 0, 0)

// ---------------- kernel 0: merged prep (blocks 0..511) + qstats (512..1535)
// bpk: per (b, 32-k image): 208 rows x 40-short pitch (16640 B / image).
// rows [0,64): q*w_cq, [64,128): q*W3c0, [128,192): q*W3c1,
// 192: w_c, 193: W1c0, 194: W1c1. rows 195..207 poison (harmless).
__global__ __launch_bounds__(256) void k_pq(
    const float* __restrict__ q, const float* __restrict__ w_cq,
    const float* __restrict__ w_c, const float* __restrict__ w_q,
    const float* __restrict__ W_out, unsigned short* __restrict__ bpk,
    float* __restrict__ qstats) {
  const int t = threadIdx.x;
  if (blockIdx.x < 512) {
    const int s = blockIdx.x & 31, b = blockIdx.x >> 5;  // s = 64-k step
    const int k0 = s * 64;
    unsigned short* base = bpk + (size_t)b * NIMG * IST;
#pragma unroll
    for (int i = 0; i < 4; ++i) {
      int idx = t + 256 * i;  // 0..1023
      int qi = idx >> 4, kc = (idx & 15) * 4;  // kc in [0,64)
      unsigned short* img = base + (size_t)(s * 2 + (kc >> 5)) * IST;
      const int ko = kc & 31;
      float4 qv = *(const float4*)(q + ((size_t)b * Q + qi) * D + k0 + kc);
      float4 wq = *(const float4*)(w_cq + k0 + kc);
      const float* wp = W_out + (size_t)(2 * D + k0 + kc) * 2;  // W3 rows
      float4 wa = *(const float4*)(wp);
      float4 wb = *(const float4*)(wp + 4);
      uint2 u;
      u.x = pkbf(qv.x * wq.x, qv.y * wq.y);
      u.y = pkbf(qv.z * wq.z, qv.w * wq.w);
      *(uint2*)(img + qi * PITCH + ko) = u;
      u.x = pkbf(qv.x * wa.x, qv.y * wa.z);
      u.y = pkbf(qv.z * wb.x, qv.w * wb.z);
      *(uint2*)(img + (64 + qi) * PITCH + ko) = u;
      u.x = pkbf(qv.x * wa.y, qv.y * wa.w);
      u.y = pkbf(qv.z * wb.y, qv.w * wb.w);
      *(uint2*)(img + (128 + qi) * PITCH + ko) = u;
    }
    if (t < 48) {  // stats rows 192..194
      int r = t >> 4, kc = (t & 15) * 4;
      unsigned short* img = base + (size_t)(s * 2 + (kc >> 5)) * IST;
      const int ko = kc & 31;
      uint2 u;
      if (r == 0) {
        float4 w = *(const float4*)(w_c + k0 + kc);
        u.x = pkbf(w.x, w.y);
        u.y = pkbf(w.z, w.w);
      } else {
        const float* wp = W_out + (size_t)(k0 + kc) * 2 + (r - 1);  // W1 col
        u.x = pkbf(wp[0], wp[2]);
        u.y = pkbf(wp[4], wp[6]);
      }
      *(uint2*)(img + (192 + r) * PITCH + ko) = u;
    }
  } else {
    int bi = blockIdx.x - 512;
    const float* qrow = q + (size_t)bi * D;
    float a0 = 0.f, a1 = 0.f, a2 = 0.f;
    for (int d = t * 4; d < D; d += 256 * 4) {
      float4 qv = *(const float4*)(qrow + d);
      float4 wq = *(const float4*)(w_q + d);
      const float* wp = W_out + (size_t)(D + d) * 2;
      float4 wa = *(const float4*)(wp);
      float4 wb = *(const float4*)(wp + 4);
      a0 += qv.x * wq.x + qv.y * wq.y + qv.z * wq.z + qv.w * wq.w;
      a1 += qv.x * wa.x + qv.y * wa.z + qv.z * wb.x + qv.w * wb.z;
      a2 += qv.x * wa.y + qv.y * wa.w + qv.z * wb.y + qv.w * wb.w;
    }
    for (int m = 1; m < 64; m <<= 1) {
      a0 += __shfl_xor(a0, m, 64);
      a1 += __shfl_xor(a1, m, 64);
      a2 += __shfl_xor(a2, m, 64);
    }
    __shared__ float red[3][4];
    int w = t >> 6, lane = t & 63;
    if (lane == 0) { red[0][w] = a0; red[1][w] = a1; red[2][w] = a2; }
    __syncthreads();
    if (t == 0) {
      qstats[bi * 3 + 0] = red[0][0] + red[0][1] + red[0][2] + red[0][3];
      qstats[bi * 3 + 1] = red[1][0] + red[1][1] + red[1][2] + red[1][3];
      qstats[bi * 3 + 2] = red[2][0] + red[2][1] + red[2][2] + red[2][3];
    }
  }
}

// ---------------- kernel 1: transposed split-K MFMA score GEMM --------------
// Per block: M = 208 pack rows (13 frags), N = 96 c-rows, K = 256 (8 steps).
// flat grid 512 = (n:4)x(kc:8)x(b:16), b fastest -> 2 blocks/CU for TLP.
// 512 thr = 8 waves (4 M-grp x 2 N-grp). Side-product: bf16 c copy (cbf).
__global__ __launch_bounds__(512, 2) void k_score(
    const unsigned short* __restrict__ bpk, const float* __restrict__ c,
    float* __restrict__ S3p, unsigned short* __restrict__ cbf) {
  const int t = threadIdx.x;
  const int lane = t & 63, wv = t >> 6;
  const int bid = blockIdx.x;
  const int b = bid & 15, kcb = (bid >> 4) & 7, n0 = (bid >> 7) * NT;
  const int lr = lane & 15, lg = lane >> 4;
  const int mg = wv >> 1, ng = wv & 1;

  __shared__ unsigned short sBp[2][IST];        // 2 x 16640 B (pack)
  __shared__ unsigned short sCp[2][NT * PITCH]; // 2 x 7680 B  (c rows)

  const unsigned short* gB = bpk + ((size_t)b * NIMG + kcb * 8) * IST;
  const float* cbase = c + ((size_t)b * C + n0) * D + kcb * 256;
  unsigned short* cbf_base = cbf + ((size_t)b * C + n0) * D + kcb * 256;

  f32x4 acc[4][3];
#pragma unroll
  for (int f = 0; f < 4; ++f)
#pragma unroll
    for (int g = 0; g < 3; ++g) acc[f][g] = f32x4{0.f, 0.f, 0.f, 0.f};

  auto stageB = [&](int buf, int s) {
    const char* src = (const char*)gB + (size_t)s * (IST * 2);
    char* dst = (char*)&sBp[buf][0];
    GLD_LDS(src + t * 16, dst + t * 16);
    GLD_LDS(src + 8192 + t * 16, dst + 8192 + t * 16);
    if (t < 16) GLD_LDS(src + 16384 + t * 16, dst + 16384 + t * 16);
  };
  auto loadC = [&](float4* r, int s) {
    const float* base = cbase + s * 32;
    if (wv < 4) {
      int g0 = wv * 128 + lane;
      r[0] = *(const float4*)(base + (size_t)(g0 >> 3) * D + (g0 & 7) * 4);
      int g1 = g0 + 64;
      r[1] = *(const float4*)(base + (size_t)(g1 >> 3) * D + (g1 & 7) * 4);
    } else {
      int g0 = 512 + (wv - 4) * 64 + lane;
      r[0] = *(const float4*)(base + (size_t)(g0 >> 3) * D + (g0 & 7) * 4);
    }
  };
  auto writeC = [&](int buf, const float4* r, int s) {
    unsigned short* cb = cbf_base + s * 32;
    if (wv < 4) {
      int g0 = wv * 128 + lane;
      uint2 u0 = {pkbf(r[0].x, r[0].y), pkbf(r[0].z, r[0].w)};
      *(uint2*)&sCp[buf][(g0 >> 3) * PITCH + (g0 & 7) * 4] = u0;
      *(uint2*)(cb + (size_t)(g0 >> 3) * D + (g0 & 7) * 4) = u0;
      int g1 = g0 + 64;
      uint2 u1 = {pkbf(r[1].x, r[1].y), pkbf(r[1].z, r[1].w)};
      *(uint2*)&sCp[buf][(g1 >> 3) * PITCH + (g1 & 7) * 4] = u1;
      *(uint2*)(cb + (size_t)(g1 >> 3) * D + (g1 & 7) * 4) = u1;
    } else {
      int g0 = 512 + (wv - 4) * 64 + lane;
      uint2 u0 = {pkbf(r[0].x, r[0].y), pkbf(r[0].z, r[0].w)};
      *(uint2*)&sCp[buf][(g0 >> 3) * PITCH + (g0 & 7) * 4] = u0;
      *(uint2*)(cb + (size_t)(g0 >> 3) * D + (g0 & 7) * 4) = u0;
    }
  };
  auto compute = [&](int buf) {
    s16x8 af[4], bf[3];
#pragma unroll
    for (int f = 0; f < 4; ++f)
      af[f] = *(const s16x8*)&sBp[buf][(mg * 64 + f * 16 + lr) * PITCH +
                                       lg * 8];
#pragma unroll
    for (int g = 0; g < 3; ++g)
      bf[g] = *(const s16x8*)&sCp[buf][((ng * 3 + g) * 16 + lr) * PITCH +
                                       lg * 8];
    __builtin_amdgcn_s_setprio(1);
#pragma unroll
    for (int f = 0; f < 4; ++f)
#pragma unroll
      for (int g = 0; g < 3; ++g)
        acc[f][g] =
            __builtin_amdgcn_mfma_f32_16x16x32_bf16(af[f], bf[g], acc[f][g],
                                                    0, 0, 0);
    __builtin_amdgcn_s_setprio(0);
  };

  // per-wave in-flight target (next step's glds + c loads stay outstanding)
  const int nvm = (wv == 0) ? 5 : ((wv < 4) ? 4 : 3);

  float4 rc[2][2];
  stageB(0, 0);
  loadC(rc[0], 0);
  for (int s = 0; s < 8; ++s) {
    const int cur = s & 1;
    if (s + 1 < 8) {
      stageB(cur ^ 1, s + 1);
      loadC(rc[cur ^ 1], s + 1);
      if (nvm == 5)
        asm volatile("s_waitcnt vmcnt(5)" ::: "memory");
      else if (nvm == 4)
        asm volatile("s_waitcnt vmcnt(4)" ::: "memory");
      else
        asm volatile("s_waitcnt vmcnt(3)" ::: "memory");
    } else {
      asm volatile("s_waitcnt vmcnt(0)" ::: "memory");
    }
    writeC(cur, rc[cur], s);
    asm volatile("s_waitcnt lgkmcnt(0)" ::: "memory");
    __builtin_amdgcn_sched_barrier(0);
    __builtin_amdgcn_s_barrier();  // publish buffers(cur)
    compute(cur);
    __builtin_amdgcn_s_barrier();  // buffers(cur) free
  }

  // epilogue: store real pack frags (mf < 13) to this kc's partial buffer
  const size_t rowbase = ((size_t)kcb * B + b) * C;
#pragma unroll
  for (int f = 0; f < 4; ++f) {
    int mf = mg * 4 + f;
    if (mf < 13) {
#pragma unroll
      for (int g = 0; g < 3; ++g) {
        int n = n0 + (ng * 3 + g) * 16 + lr;
        float* p = S3p + (rowbase + n) * SP + mf * 16 + lg * 4;
        *(f32x4*)p = acc[f][g];
      }
    }
  }
}

// ---------------- kernel 2: sum partials + row softmax + reductions ---------
__global__ __launch_bounds__(256) void k_soft(
    const float* __restrict__ S3p, const float* __restrict__ qstats,
    const int* __restrict__ c_len, const int* __restrict__ q_len,
    const float* __restrict__ b_c, const float* __restrict__ b_q,
    const float* __restrict__ b_cq, float* __restrict__ mrow,
    float* __restrict__ out12) {
  const int t = threadIdx.x, lane = t & 63;
  const int rg = blockIdx.x * 4 + (t >> 6);  // b*C + r
  const int b = rg / C, r = rg % C;
  float s_cq = 0.f, sc = 0.f, w10 = 0.f, w11 = 0.f, t30 = 0.f, t31 = 0.f;
#pragma unroll
  for (int p = 0; p < KC; ++p) {
    const float* Sr = S3p + ((size_t)p * B * C + rg) * SP;
    s_cq += Sr[lane];
    sc += Sr[192];
    w10 += Sr[193];
    w11 += Sr[194];
    t30 += Sr[64 + lane];
    t31 += Sr[128 + lane];
  }
  const float qs0 = qstats[((b << 6) + lane) * 3 + 0];
  const float qs1 = qstats[((b << 6) + lane) * 3 + 1];
  const float qs2 = qstats[((b << 6) + lane) * 3 + 2];
  float s = s_cq + sc + qs0 + b_c[0] + b_q[0] + b_cq[0];
  const int cl = c_len[b], ql = q_len[b];
  bool masked = (lane >= ql) || ((r >= cl) && (lane < Q - 1));
  if (masked) s += NEGV;
  float mx = s;
  for (int m = 1; m < 64; m <<= 1) mx = fmaxf(mx, __shfl_xor(mx, m, 64));
  float e = __expf(s - mx);
  float den = e;
  for (int m = 1; m < 64; m <<= 1) den += __shfl_xor(den, m, 64);
  float a = e / den;
  float v0 = a * (qs1 + t30);
  float v1 = a * (qs2 + t31);
  for (int m = 1; m < 64; m <<= 1) {
    v0 += __shfl_xor(v0, m, 64);
    v1 += __shfl_xor(v1, m, 64);
  }
  if (lane == 0) {
    mrow[rg] = mx;
    out12[rg * 2 + 0] = w10 + v0;
    out12[rg * 2 + 1] = w11 + v1;
  }
}

// ---------------- kernel 3: q2c GEMV (bf16 c) fused with W4 -> u vectors ----
// grid (16 d-chunks of 128, B), 512 thr (8 waves). lane owns d-pair.
__global__ __launch_bounds__(512) void k_q2cu(
    const unsigned short* __restrict__ cbf, const float* __restrict__ mrow,
    const float* __restrict__ W_out, float* __restrict__ uvec) {
  const int ch = blockIdx.x, b = blockIdx.y;
  const int t = threadIdx.x, lane = t & 63, wv = t >> 6;
  __shared__ float batt[C];
  __shared__ float rmx[8], rsm[8];
  __shared__ float redq0[8][64], redq1[8][64];

  float m = (t < C) ? mrow[b * C + t] : -3.0e38f;
  float mx = m;
  for (int o = 1; o < 64; o <<= 1) mx = fmaxf(mx, __shfl_xor(mx, o, 64));
  if (lane == 0) rmx[wv] = mx;
  __syncthreads();
  mx = rmx[0];
#pragma unroll
  for (int i = 1; i < 8; ++i) mx = fmaxf(mx, rmx[i]);
  float e = (t < C) ? __expf(m - mx) : 0.f;
  float sm = e;
  for (int o = 1; o < 64; o <<= 1) sm += __shfl_xor(sm, o, 64);
  if (lane == 0) rsm[wv] = sm;
  __syncthreads();
  sm = rsm[0] + rsm[1] + rsm[2] + rsm[3] + rsm[4] + rsm[5] + rsm[6] + rsm[7];
  if (t < C) batt[t] = e / sm;
  __syncthreads();

  const int d0 = ch * 128 + lane * 2;
  const unsigned short* p = cbf + ((size_t)b * C + wv * 8) * D + d0;
  float A0[8] = {0.f, 0.f, 0.f, 0.f, 0.f, 0.f, 0.f, 0.f};
  float A1[8] = {0.f, 0.f, 0.f, 0.f, 0.f, 0.f, 0.f, 0.f};
#pragma unroll
  for (int r0 = 0; r0 < 384; r0 += 64) {
    const unsigned short* pr = p + (size_t)r0 * D;
    const float* bt = &batt[r0 + wv * 8];
#pragma unroll
    for (int j = 0; j < 8; ++j) {
      unsigned cc = *(const unsigned*)(pr + (size_t)j * D);
      A0[j] += bt[j] * bflo(cc);
      A1[j] += bt[j] * bfhi(cc);
    }
  }
  float s0 = ((A0[0] + A0[1]) + (A0[2] + A0[3])) +
             ((A0[4] + A0[5]) + (A0[6] + A0[7]));
  float s1 = ((A1[0] + A1[1]) + (A1[2] + A1[3])) +
             ((A1[4] + A1[5]) + (A1[6] + A1[7]));
  redq0[wv][lane] = s0;
  redq1[wv][lane] = s1;
  __syncthreads();
  if (t < 64) {
    float q0 = 0.f, q1 = 0.f;
#pragma unroll
    for (int w = 0; w < 8; ++w) {
      q0 += redq0[w][t];
      q1 += redq1[w][t];
    }
    int dd = ch * 128 + t * 2;
    float4 w4 = *(const float4*)(W_out + (size_t)(3 * D + dd) * 2);
    float4 u = {q0 * w4.x, q0 * w4.y, q1 * w4.z, q1 * w4.w};
    *(float4*)(uvec + ((size_t)b * D + dd) * 2) = u;
  }
}

// ---------------- kernel 4: term4 row-dots (bf16 c) + bias + mask + write ---
// grid (C/8=48, B), 512 thr (8 waves), wave per row; u staged in LDS.
__global__ __launch_bounds__(512) void k_out(
    const unsigned short* __restrict__ cbf, const float* __restrict__ uvec,
    const float* __restrict__ out12, const float* __restrict__ b_out,
    const int* __restrict__ c_len, float* __restrict__ outp) {
  const int b = blockIdx.y, r0 = blockIdx.x * 8;
  const int t = threadIdx.x, lane = t & 63, wv = t >> 6;
  __shared__ float u_sh[2 * D];  // interleaved {u0,u1} pairs

  {
    const float* src = uvec + (size_t)b * D * 2 + t * 8;
    float4 v0 = *(const float4*)(src);
    float4 v1 = *(const float4*)(src + 4);
    *(float4*)&u_sh[t * 8] = v0;
    *(float4*)&u_sh[t * 8 + 4] = v1;
  }
  __syncthreads();

  const int r = r0 + wv;
  const unsigned short* crow = cbf + ((size_t)b * C + r) * D;
  float o0 = 0.f, o1 = 0.f;
#pragma unroll
  for (int it = 0; it < 16; ++it) {
    int d0 = it * 128 + lane * 2;
    unsigned cc = *(const unsigned*)(crow + d0);
    float c0 = bflo(cc), c1 = bfhi(cc);
    float4 u = *(const float4*)&u_sh[d0 * 2];
    o0 += c0 * u.x + c1 * u.z;
    o1 += c0 * u.y + c1 * u.w;
  }
  for (int o = 1; o < 64; o <<= 1) {
    o0 += __shfl_xor(o0, o, 64);
    o1 += __shfl_xor(o1, o, 64);
  }
  if (lane == 0) {
    const int idx = b * C + r;
    o0 += out12[idx * 2 + 0] + b_out[0];
    o1 += out12[idx * 2 + 1] + b_out[1];
    if (r >= c_len[b] && r < C - 1) { o0 = NEGV; o1 = NEGV; }
    outp[idx] = o0;
    outp[B * C + idx] = o1;
  }
}

extern "C" void kernel_launch(void* const* d_in, const int* in_sizes, int n_in,
                              void* d_out, int out_size, void* d_ws,
                              size_t ws_size, hipStream_t stream) {
  const float* c = (const float*)d_in[0];
  const float* q = (const float*)d_in[1];
  const int* c_len = (const int*)d_in[2];
  const int* q_len = (const int*)d_in[3];
  const float* w_c = (const float*)d_in[4];
  const float* b_c = (const float*)d_in[5];
  const float* w_q = (const float*)d_in[6];
  const float* b_q = (const float*)d_in[7];
  const float* w_cq = (const float*)d_in[8];
  const float* b_cq = (const float*)d_in[9];
  const float* W_out = (const float*)d_in[10];
  const float* b_out = (const float*)d_in[11];
  float* outp = (float*)d_out;

  // ws: bpk (17 MB) | S3 partials (40.9 MB) | smalls | uvec | c_bf (25 MB)
  unsigned short* bpk = (unsigned short*)d_ws;
  const size_t bpk_bytes = (size_t)B * NIMG * IST * 2;  // 17,039,360
  float* S3p = (float*)((char*)d_ws + bpk_bytes);
  const size_t s3_elems = (size_t)KC * B * C * SP;      // 10,223,616
  float* ws = S3p + s3_elems;
  float* qstats = ws;                     // B*Q*3  = 3072
  float* mrow = ws + 3072;                // B*C    = 6144
  float* out12 = ws + 3072 + 6144;        // B*C*2  = 12288
  float* uvec = ws + 3072 + 6144 + 12288; // B*D*2  = 65536
  unsigned short* cbf = (unsigned short*)(uvec + 65536);  // B*C*D bf16

  hipLaunchKernelGGL(k_pq, dim3(512 + B * Q), dim3(256), 0, stream, q, w_cq,
                     w_c, w_q, W_out, bpk, qstats);
  hipLaunchKernelGGL(k_score, dim3(4 * KC * B), dim3(512), 0, stream, bpk, c,
                     S3p, cbf);
  hipLaunchKernelGGL(k_soft, dim3(B * C / 4), dim3(256), 0, stream, S3p,
                     qstats, c_len, q_len, b_c, b_q, b_cq, mrow, out12);
  hipLaunchKernelGGL(k_q2cu, dim3(16, B), dim3(512), 0, stream, cbf, mrow,
                     W_out, uvec);
  hipLaunchKernelGGL(k_out, dim3(C / 8, B), dim3(512), 0, stream, cbf, uvec,
                     out12, b_out, c_len, outp);
}

// Round 14
// 47.908 us; speedup vs baseline: 1.1035x; 1.1035x over previous
//
#include <hip/hip_runtime.h>

#define NEGV -1.0e12f
constexpr int B = 16, C = 384, Q = 64, D = 2048;
constexpr int PITCH = 40;      // shorts per packed row (80 B, 2-way banks)
constexpr int IST = 8320;      // shorts per 32-k image (208 rows x 40 = 16640 B)
constexpr int NIMG = 64;       // 32-k images per batch
constexpr int NT = 96;         // c-rows per k_score block (n-tile)
constexpr int KC = 4;          // split-K chunks (512 k each, 16 images)
constexpr int SP = 208;        // S3 partial col pitch (shorts)

typedef __attribute__((ext_vector_type(8))) short s16x8;
typedef __attribute__((ext_vector_type(4))) float f32x4;

__device__ __forceinline__ unsigned pkbf(float lo, float hi) {
  unsigned ulo = __builtin_bit_cast(unsigned, lo);
  unsigned uhi = __builtin_bit_cast(unsigned, hi);
  return (uhi & 0xFFFF0000u) | (ulo >> 16);
}
__device__ __forceinline__ float bflo(unsigned u) {
  return __builtin_bit_cast(float, u << 16);
}
__device__ __forceinline__ float bfhi(unsigned u) {
  return __builtin_bit_cast(float, u & 0xFFFF0000u);
}
__device__ __forceinline__ float bfs(unsigned short u) {
  return __builtin_bit_cast(float, ((unsigned)u) << 16);
}

#define GLD_LDS(gsrc, ldst)                                              \
  __builtin_amdgcn_global_load_lds(                                      \
      (const __attribute__((address_space(1))) unsigned*)(gsrc),         \
      (__attribute__((address_space(3))) unsigned*)(ldst), 16, 0, 0)

// ---------------- kernel 0: merged prep (blocks 0..511) + qstats (512..1535)
// bpk: per (b, 32-k image): 208 rows x 40-short pitch (16640 B / image).
// rows [0,64): q*w_cq, [64,128): q*W3c0, [128,192): q*W3c1,
// 192: w_c, 193: W1c0, 194: W1c1. rows 195..207 poison (harmless).
__global__ __launch_bounds__(256) void k_pq(
    const float* __restrict__ q, const float* __restrict__ w_cq,
    const float* __restrict__ w_c, const float* __restrict__ w_q,
    const float* __restrict__ W_out, unsigned short* __restrict__ bpk,
    float* __restrict__ qstats) {
  const int t = threadIdx.x;
  if (blockIdx.x < 512) {
    const int s = blockIdx.x & 31, b = blockIdx.x >> 5;  // s = 64-k step
    const int k0 = s * 64;
    unsigned short* base = bpk + (size_t)b * NIMG * IST;
#pragma unroll
    for (int i = 0; i < 4; ++i) {
      int idx = t + 256 * i;  // 0..1023
      int qi = idx >> 4, kc = (idx & 15) * 4;  // kc in [0,64)
      unsigned short* img = base + (size_t)(s * 2 + (kc >> 5)) * IST;
      const int ko = kc & 31;
      float4 qv = *(const float4*)(q + ((size_t)b * Q + qi) * D + k0 + kc);
      float4 wq = *(const float4*)(w_cq + k0 + kc);
      const float* wp = W_out + (size_t)(2 * D + k0 + kc) * 2;  // W3 rows
      float4 wa = *(const float4*)(wp);
      float4 wb = *(const float4*)(wp + 4);
      uint2 u;
      u.x = pkbf(qv.x * wq.x, qv.y * wq.y);
      u.y = pkbf(qv.z * wq.z, qv.w * wq.w);
      *(uint2*)(img + qi * PITCH + ko) = u;
      u.x = pkbf(qv.x * wa.x, qv.y * wa.z);
      u.y = pkbf(qv.z * wb.x, qv.w * wb.z);
      *(uint2*)(img + (64 + qi) * PITCH + ko) = u;
      u.x = pkbf(qv.x * wa.y, qv.y * wa.w);
      u.y = pkbf(qv.z * wb.y, qv.w * wb.w);
      *(uint2*)(img + (128 + qi) * PITCH + ko) = u;
    }
    if (t < 48) {  // stats rows 192..194
      int r = t >> 4, kc = (t & 15) * 4;
      unsigned short* img = base + (size_t)(s * 2 + (kc >> 5)) * IST;
      const int ko = kc & 31;
      uint2 u;
      if (r == 0) {
        float4 w = *(const float4*)(w_c + k0 + kc);
        u.x = pkbf(w.x, w.y);
        u.y = pkbf(w.z, w.w);
      } else {
        const float* wp = W_out + (size_t)(k0 + kc) * 2 + (r - 1);  // W1 col
        u.x = pkbf(wp[0], wp[2]);
        u.y = pkbf(wp[4], wp[6]);
      }
      *(uint2*)(img + (192 + r) * PITCH + ko) = u;
    }
  } else {
    int bi = blockIdx.x - 512;
    const float* qrow = q + (size_t)bi * D;
    float a0 = 0.f, a1 = 0.f, a2 = 0.f;
    for (int d = t * 4; d < D; d += 256 * 4) {
      float4 qv = *(const float4*)(qrow + d);
      float4 wq = *(const float4*)(w_q + d);
      const float* wp = W_out + (size_t)(D + d) * 2;
      float4 wa = *(const float4*)(wp);
      float4 wb = *(const float4*)(wp + 4);
      a0 += qv.x * wq.x + qv.y * wq.y + qv.z * wq.z + qv.w * wq.w;
      a1 += qv.x * wa.x + qv.y * wa.z + qv.z * wb.x + qv.w * wb.z;
      a2 += qv.x * wa.y + qv.y * wa.w + qv.z * wb.y + qv.w * wb.w;
    }
    for (int m = 1; m < 64; m <<= 1) {
      a0 += __shfl_xor(a0, m, 64);
      a1 += __shfl_xor(a1, m, 64);
      a2 += __shfl_xor(a2, m, 64);
    }
    __shared__ float red[3][4];
    int w = t >> 6, lane = t & 63;
    if (lane == 0) { red[0][w] = a0; red[1][w] = a1; red[2][w] = a2; }
    __syncthreads();
    if (t == 0) {
      qstats[bi * 3 + 0] = red[0][0] + red[0][1] + red[0][2] + red[0][3];
      qstats[bi * 3 + 1] = red[1][0] + red[1][1] + red[1][2] + red[1][3];
      qstats[bi * 3 + 2] = red[2][0] + red[2][1] + red[2][2] + red[2][3];
    }
  }
}

// ---------------- kernel 1: transposed split-K MFMA score GEMM --------------
// Per block: M = 208 pack rows (13 frags), N = 96 c-rows, K = 512 (16 steps).
// flat grid 256 = (n:4)x(kc:4)x(b:16), b fastest. 512 thr = 8 waves
// (4 M-grp x 2 N-grp). 3 LDS buffers, prefetch depth 2 (counted vmcnt
// includes cbf stores which share the vmcnt counter). bf16 c side-product.
__global__ __launch_bounds__(512, 1) void k_score(
    const unsigned short* __restrict__ bpk, const float* __restrict__ c,
    unsigned short* __restrict__ S3pb, unsigned short* __restrict__ cbf) {
  const int t = threadIdx.x;
  const int lane = t & 63, wv = t >> 6;
  const int bid = blockIdx.x;
  const int b = bid & 15, kcb = (bid >> 4) & 3, n0 = (bid >> 6) * NT;
  const int lr = lane & 15, lg = lane >> 4;
  const int mg = wv >> 1, ng = wv & 1;

  __shared__ unsigned short sBp[3][IST];        // 3 x 16640 B (pack)
  __shared__ unsigned short sCp[3][NT * PITCH]; // 3 x 7680 B  (c rows)

  const unsigned short* gB = bpk + ((size_t)b * NIMG + kcb * 16) * IST;
  const float* cbase = c + ((size_t)b * C + n0) * D + kcb * 512;
  unsigned short* cbf_base = cbf + ((size_t)b * C + n0) * D + kcb * 512;

  f32x4 acc[4][3];
#pragma unroll
  for (int f = 0; f < 4; ++f)
#pragma unroll
    for (int g = 0; g < 3; ++g) acc[f][g] = f32x4{0.f, 0.f, 0.f, 0.f};

  auto stageB = [&](int buf, int s) {
    const char* src = (const char*)gB + (size_t)s * (IST * 2);
    char* dst = (char*)&sBp[buf][0];
    GLD_LDS(src + t * 16, dst + t * 16);
    GLD_LDS(src + 8192 + t * 16, dst + 8192 + t * 16);
    if (t < 16) GLD_LDS(src + 16384 + t * 16, dst + 16384 + t * 16);
  };
  auto loadC = [&](float4* r, int s) {
    const float* base = cbase + s * 32;
    if (wv < 4) {
      int g0 = wv * 128 + lane;
      r[0] = *(const float4*)(base + (size_t)(g0 >> 3) * D + (g0 & 7) * 4);
      int g1 = g0 + 64;
      r[1] = *(const float4*)(base + (size_t)(g1 >> 3) * D + (g1 & 7) * 4);
    } else {
      int g0 = 512 + (wv - 4) * 64 + lane;
      r[0] = *(const float4*)(base + (size_t)(g0 >> 3) * D + (g0 & 7) * 4);
    }
  };
  auto writeC = [&](int buf, const float4* r, int s) {
    unsigned short* cb = cbf_base + s * 32;
    if (wv < 4) {
      int g0 = wv * 128 + lane;
      uint2 u0 = {pkbf(r[0].x, r[0].y), pkbf(r[0].z, r[0].w)};
      *(uint2*)&sCp[buf][(g0 >> 3) * PITCH + (g0 & 7) * 4] = u0;
      *(uint2*)(cb + (size_t)(g0 >> 3) * D + (g0 & 7) * 4) = u0;
      int g1 = g0 + 64;
      uint2 u1 = {pkbf(r[1].x, r[1].y), pkbf(r[1].z, r[1].w)};
      *(uint2*)&sCp[buf][(g1 >> 3) * PITCH + (g1 & 7) * 4] = u1;
      *(uint2*)(cb + (size_t)(g1 >> 3) * D + (g1 & 7) * 4) = u1;
    } else {
      int g0 = 512 + (wv - 4) * 64 + lane;
      uint2 u0 = {pkbf(r[0].x, r[0].y), pkbf(r[0].z, r[0].w)};
      *(uint2*)&sCp[buf][(g0 >> 3) * PITCH + (g0 & 7) * 4] = u0;
      *(uint2*)(cb + (size_t)(g0 >> 3) * D + (g0 & 7) * 4) = u0;
    }
  };
  auto compute = [&](int buf) {
    s16x8 af[4], bf[3];
#pragma unroll
    for (int f = 0; f < 4; ++f)
      af[f] = *(const s16x8*)&sBp[buf][(mg * 64 + f * 16 + lr) * PITCH +
                                       lg * 8];
#pragma unroll
    for (int g = 0; g < 3; ++g)
      bf[g] = *(const s16x8*)&sCp[buf][((ng * 3 + g) * 16 + lr) * PITCH +
                                       lg * 8];
#pragma unroll
    for (int f = 0; f < 4; ++f)
#pragma unroll
      for (int g = 0; g < 3; ++g)
        acc[f][g] =
            __builtin_amdgcn_mfma_f32_16x16x32_bf16(af[f], bf[g], acc[f][g],
                                                    0, 0, 0);
  };

  // vmcnt targets: loads/step {5,4,3} + stores/step {2,2,1} per wave group.
  auto vmwait2 = [&]() {  // depth-2 steady state: 2*loads + 2*stores
    if (wv == 0)
      asm volatile("s_waitcnt vmcnt(14)" ::: "memory");
    else if (wv < 4)
      asm volatile("s_waitcnt vmcnt(12)" ::: "memory");
    else
      asm volatile("s_waitcnt vmcnt(8)" ::: "memory");
  };
  auto vmwait1 = [&]() {  // tail: 1*loads + 1*stores
    if (wv == 0)
      asm volatile("s_waitcnt vmcnt(7)" ::: "memory");
    else if (wv < 4)
      asm volatile("s_waitcnt vmcnt(6)" ::: "memory");
    else
      asm volatile("s_waitcnt vmcnt(4)" ::: "memory");
  };

  float4 rc[3][2];
  stageB(0, 0);
  loadC(rc[0], 0);
  stageB(1, 1);
  loadC(rc[1], 1);
#pragma unroll
  for (int s = 0; s < 16; ++s) {
    const int cur = s % 3;
    if (s + 2 < 16) {
      stageB((s + 2) % 3, s + 2);
      loadC(rc[(s + 2) % 3], s + 2);
      vmwait2();
    } else if (s + 1 < 16) {
      vmwait1();
    } else {
      asm volatile("s_waitcnt vmcnt(0)" ::: "memory");
    }
    writeC(cur, rc[cur], s);
    asm volatile("s_waitcnt lgkmcnt(0)" ::: "memory");
    __builtin_amdgcn_sched_barrier(0);
    __builtin_amdgcn_s_barrier();  // publish buffers(cur)
    compute(cur);
    __builtin_amdgcn_s_barrier();  // buffers(cur) free for stage(s+3)
  }

  // epilogue: bf16-pack real frags (mf < 13) to this kc's partial buffer
  const size_t rowbase = ((size_t)kcb * B + b) * C;
#pragma unroll
  for (int f = 0; f < 4; ++f) {
    int mf = mg * 4 + f;
    if (mf < 13) {
#pragma unroll
      for (int g = 0; g < 3; ++g) {
        int n = n0 + (ng * 3 + g) * 16 + lr;
        uint2 pk;
        pk.x = pkbf(acc[f][g][0], acc[f][g][1]);
        pk.y = pkbf(acc[f][g][2], acc[f][g][3]);
        *(uint2*)(S3pb + (rowbase + n) * SP + mf * 16 + lg * 4) = pk;
      }
    }
  }
}

// ---------------- kernel 2: sum partials + row softmax + reductions ---------
__global__ __launch_bounds__(256) void k_soft(
    const unsigned short* __restrict__ S3pb, const float* __restrict__ qstats,
    const int* __restrict__ c_len, const int* __restrict__ q_len,
    const float* __restrict__ b_c, const float* __restrict__ b_q,
    const float* __restrict__ b_cq, float* __restrict__ mrow,
    float* __restrict__ out12) {
  const int t = threadIdx.x, lane = t & 63;
  const int rg = blockIdx.x * 4 + (t >> 6);  // b*C + r
  const int b = rg / C, r = rg % C;
  float s_cq = 0.f, sc = 0.f, w10 = 0.f, w11 = 0.f, t30 = 0.f, t31 = 0.f;
#pragma unroll
  for (int p = 0; p < KC; ++p) {
    const unsigned short* Sr = S3pb + ((size_t)p * B * C + rg) * SP;
    s_cq += bfs(Sr[lane]);
    sc += bfs(Sr[192]);
    w10 += bfs(Sr[193]);
    w11 += bfs(Sr[194]);
    t30 += bfs(Sr[64 + lane]);
    t31 += bfs(Sr[128 + lane]);
  }
  const float qs0 = qstats[((b << 6) + lane) * 3 + 0];
  const float qs1 = qstats[((b << 6) + lane) * 3 + 1];
  const float qs2 = qstats[((b << 6) + lane) * 3 + 2];
  float s = s_cq + sc + qs0 + b_c[0] + b_q[0] + b_cq[0];
  const int cl = c_len[b], ql = q_len[b];
  bool masked = (lane >= ql) || ((r >= cl) && (lane < Q - 1));
  if (masked) s += NEGV;
  float mx = s;
  for (int m = 1; m < 64; m <<= 1) mx = fmaxf(mx, __shfl_xor(mx, m, 64));
  float e = __expf(s - mx);
  float den = e;
  for (int m = 1; m < 64; m <<= 1) den += __shfl_xor(den, m, 64);
  float a = e / den;
  float v0 = a * (qs1 + t30);
  float v1 = a * (qs2 + t31);
  for (int m = 1; m < 64; m <<= 1) {
    v0 += __shfl_xor(v0, m, 64);
    v1 += __shfl_xor(v1, m, 64);
  }
  if (lane == 0) {
    mrow[rg] = mx;
    out12[rg * 2 + 0] = w10 + v0;
    out12[rg * 2 + 1] = w11 + v1;
  }
}

// ---------------- kernel 3: q2c GEMV (bf16 c) fused with W4 -> u vectors ----
// grid (16 d-chunks of 128, B), 512 thr (8 waves). lane owns d-pair.
__global__ __launch_bounds__(512) void k_q2cu(
    const unsigned short* __restrict__ cbf, const float* __restrict__ mrow,
    const float* __restrict__ W_out, float* __restrict__ uvec) {
  const int ch = blockIdx.x, b = blockIdx.y;
  const int t = threadIdx.x, lane = t & 63, wv = t >> 6;
  __shared__ float batt[C];
  __shared__ float rmx[8], rsm[8];
  __shared__ float redq0[8][64], redq1[8][64];

  float m = (t < C) ? mrow[b * C + t] : -3.0e38f;
  float mx = m;
  for (int o = 1; o < 64; o <<= 1) mx = fmaxf(mx, __shfl_xor(mx, o, 64));
  if (lane == 0) rmx[wv] = mx;
  __syncthreads();
  mx = rmx[0];
#pragma unroll
  for (int i = 1; i < 8; ++i) mx = fmaxf(mx, rmx[i]);
  float e = (t < C) ? __expf(m - mx) : 0.f;
  float sm = e;
  for (int o = 1; o < 64; o <<= 1) sm += __shfl_xor(sm, o, 64);
  if (lane == 0) rsm[wv] = sm;
  __syncthreads();
  sm = rsm[0] + rsm[1] + rsm[2] + rsm[3] + rsm[4] + rsm[5] + rsm[6] + rsm[7];
  if (t < C) batt[t] = e / sm;
  __syncthreads();

  const int d0 = ch * 128 + lane * 2;
  const unsigned short* p = cbf + ((size_t)b * C + wv * 8) * D + d0;
  float A0[8] = {0.f, 0.f, 0.f, 0.f, 0.f, 0.f, 0.f, 0.f};
  float A1[8] = {0.f, 0.f, 0.f, 0.f, 0.f, 0.f, 0.f, 0.f};
#pragma unroll
  for (int r0 = 0; r0 < 384; r0 += 64) {
    const unsigned short* pr = p + (size_t)r0 * D;
    const float* bt = &batt[r0 + wv * 8];
#pragma unroll
    for (int j = 0; j < 8; ++j) {
      unsigned cc = *(const unsigned*)(pr + (size_t)j * D);
      A0[j] += bt[j] * bflo(cc);
      A1[j] += bt[j] * bfhi(cc);
    }
  }
  float s0 = ((A0[0] + A0[1]) + (A0[2] + A0[3])) +
             ((A0[4] + A0[5]) + (A0[6] + A0[7]));
  float s1 = ((A1[0] + A1[1]) + (A1[2] + A1[3])) +
             ((A1[4] + A1[5]) + (A1[6] + A1[7]));
  redq0[wv][lane] = s0;
  redq1[wv][lane] = s1;
  __syncthreads();
  if (t < 64) {
    float q0 = 0.f, q1 = 0.f;
#pragma unroll
    for (int w = 0; w < 8; ++w) {
      q0 += redq0[w][t];
      q1 += redq1[w][t];
    }
    int dd = ch * 128 + t * 2;
    float4 w4 = *(const float4*)(W_out + (size_t)(3 * D + dd) * 2);
    float4 u = {q0 * w4.x, q0 * w4.y, q1 * w4.z, q1 * w4.w};
    *(float4*)(uvec + ((size_t)b * D + dd) * 2) = u;
  }
}

// ---------------- kernel 4: term4 row-dots (bf16 c) + bias + mask + write ---
// grid (C/8=48, B), 512 thr (8 waves), wave per row; u staged in LDS.
__global__ __launch_bounds__(512) void k_out(
    const unsigned short* __restrict__ cbf, const float* __restrict__ uvec,
    const float* __restrict__ out12, const float* __restrict__ b_out,
    const int* __restrict__ c_len, float* __restrict__ outp) {
  const int b = blockIdx.y, r0 = blockIdx.x * 8;
  const int t = threadIdx.x, lane = t & 63, wv = t >> 6;
  __shared__ float u_sh[2 * D];  // interleaved {u0,u1} pairs

  {
    const float* src = uvec + (size_t)b * D * 2 + t * 8;
    float4 v0 = *(const float4*)(src);
    float4 v1 = *(const float4*)(src + 4);
    *(float4*)&u_sh[t * 8] = v0;
    *(float4*)&u_sh[t * 8 + 4] = v1;
  }
  __syncthreads();

  const int r = r0 + wv;
  const unsigned short* crow = cbf + ((size_t)b * C + r) * D;
  float o0 = 0.f, o1 = 0.f;
#pragma unroll
  for (int it = 0; it < 16; ++it) {
    int d0 = it * 128 + lane * 2;
    unsigned cc = *(const unsigned*)(crow + d0);
    float c0 = bflo(cc), c1 = bfhi(cc);
    float4 u = *(const float4*)&u_sh[d0 * 2];
    o0 += c0 * u.x + c1 * u.z;
    o1 += c0 * u.y + c1 * u.w;
  }
  for (int o = 1; o < 64; o <<= 1) {
    o0 += __shfl_xor(o0, o, 64);
    o1 += __shfl_xor(o1, o, 64);
  }
  if (lane == 0) {
    const int idx = b * C + r;
    o0 += out12[idx * 2 + 0] + b_out[0];
    o1 += out12[idx * 2 + 1] + b_out[1];
    if (r >= c_len[b] && r < C - 1) { o0 = NEGV; o1 = NEGV; }
    outp[idx] = o0;
    outp[B * C + idx] = o1;
  }
}

extern "C" void kernel_launch(void* const* d_in, const int* in_sizes, int n_in,
                              void* d_out, int out_size, void* d_ws,
                              size_t ws_size, hipStream_t stream) {
  const float* c = (const float*)d_in[0];
  const float* q = (const float*)d_in[1];
  const int* c_len = (const int*)d_in[2];
  const int* q_len = (const int*)d_in[3];
  const float* w_c = (const float*)d_in[4];
  const float* b_c = (const float*)d_in[5];
  const float* w_q = (const float*)d_in[6];
  const float* b_q = (const float*)d_in[7];
  const float* w_cq = (const float*)d_in[8];
  const float* b_cq = (const float*)d_in[9];
  const float* W_out = (const float*)d_in[10];
  const float* b_out = (const float*)d_in[11];
  float* outp = (float*)d_out;

  // ws: bpk (17 MB) | S3 partials bf16 (10.2 MB) | smalls | uvec | c_bf (25 MB)
  unsigned short* bpk = (unsigned short*)d_ws;
  const size_t bpk_bytes = (size_t)B * NIMG * IST * 2;  // 17,039,360
  unsigned short* S3pb = (unsigned short*)((char*)d_ws + bpk_bytes);
  const size_t s3_elems = (size_t)KC * B * C * SP;      // 5,111,808 shorts
  float* ws = (float*)(S3pb + s3_elems);
  float* qstats = ws;                     // B*Q*3  = 3072
  float* mrow = ws + 3072;                // B*C    = 6144
  float* out12 = ws + 3072 + 6144;        // B*C*2  = 12288
  float* uvec = ws + 3072 + 6144 + 12288; // B*D*2  = 65536
  unsigned short* cbf = (unsigned short*)(uvec + 65536);  // B*C*D bf16

  hipLaunchKernelGGL(k_pq, dim3(512 + B * Q), dim3(256), 0, stream, q, w_cq,
                     w_c, w_q, W_out, bpk, qstats);
  hipLaunchKernelGGL(k_score, dim3(4 * KC * B), dim3(512), 0, stream, bpk, c,
                     S3pb, cbf);
  hipLaunchKernelGGL(k_soft, dim3(B * C / 4), dim3(256), 0, stream, S3pb,
                     qstats, c_len, q_len, b_c, b_q, b_cq, mrow, out12);
  hipLaunchKernelGGL(k_q2cu, dim3(16, B), dim3(512), 0, stream, cbf, mrow,
                     W_out, uvec);
  hipLaunchKernelGGL(k_out, dim3(C / 8, B), dim3(512), 0, stream, cbf, uvec,
                     out12, b_out, c_len, outp);
}